// Round 1
// baseline (665.653 us; speedup 1.0000x reference)
//
#include <hip/hip_runtime.h>

#define NWIN 12800
#define PER_SAMPLE 3200   // _NX*_NY*_NZ = 40*40*2
#define NY_NZ 80          // _NY*_NZ
#define NZW 2             // _NZ

__device__ __forceinline__ void tgt_lvl(int nb, int& tgt, int& lvl) {
    if (nb < 16)          { tgt = 16;  lvl = 0; }
    else if (nb < 32)     { tgt = 32;  lvl = 1; }
    else if (nb < 64)     { tgt = 64;  lvl = 2; }
    else if (nb < 100000) { tgt = 144; lvl = 3; }
    else                  { tgt = 0;   lvl = -1; }
}

// Compute window ids for both shift configs + histogram of win0 (all kept in round 0).
__global__ void k_wins_hist0(const int4* __restrict__ coords, int N,
                             int* __restrict__ w0, int* __restrict__ w1,
                             int* __restrict__ counts0) {
    int i = blockIdx.x * blockDim.x + threadIdx.x;
    if (i >= N) return;
    int4 c = coords[i];           // (b, z, y, x)
    int b = c.x, z = c.y, y = c.z, x = c.w;
    // do_shift=false: sx=sy=12, sz=0 (SPARSE_SHAPE[2]==wz). win_z = z//1 = z.
    int wi0 = b * PER_SAMPLE + ((x + 12) / 12) * NY_NZ + ((y + 12) / 12) * NZW + z;
    // do_shift=true: sx=sy=6, sz=0.
    int wi1 = b * PER_SAMPLE + ((x + 6) / 12) * NY_NZ + ((y + 6) / 12) * NZW + z;
    w0[i] = wi0;
    w1[i] = wi1;
    atomicAdd(&counts0[wi0], 1);
}

// Exclusive scan over NWIN=12800 counts -> starts, and copy to cursor.
// One block, 256 threads x 50 elements.
__global__ void k_scan(const int* __restrict__ counts,
                       int* __restrict__ starts, int* __restrict__ cursor) {
    __shared__ int ssum[256];
    const int CH = NWIN / 256;   // 50
    int t = threadIdx.x;
    int base = t * CH;
    int s = 0;
    for (int k = 0; k < CH; ++k) s += counts[base + k];
    ssum[t] = s;
    __syncthreads();
    for (int off = 1; off < 256; off <<= 1) {
        int v = (t >= off) ? ssum[t - off] : 0;
        __syncthreads();
        ssum[t] += v;
        __syncthreads();
    }
    int run = ssum[t] - s;       // exclusive base for this chunk
    for (int k = 0; k < CH; ++k) {
        starts[base + k] = run;
        cursor[base + k] = run;
        run += counts[base + k];
    }
}

// Round-0 scatter: all voxels.
__global__ void k_scatter0(const int* __restrict__ w0, int N,
                           int* __restrict__ cursor, int* __restrict__ sorted) {
    int i = blockIdx.x * blockDim.x + threadIdx.x;
    if (i >= N) return;
    int pos = atomicAdd(&cursor[w0[i]], 1);
    sorted[pos] = i;
}

// Per-window stable rank: inner[v] = #elements in same window with smaller index.
// One wave (64 threads) per window.
__global__ void k_rank(const int* __restrict__ starts, const int* __restrict__ counts,
                       const int* __restrict__ sorted, int* __restrict__ inner) {
    __shared__ int seg[1024];
    int w = blockIdx.x;
    int L = counts[w];
    if (L == 0) return;
    int s = starts[w];
    int lane = threadIdx.x;
    if (L <= 1024) {
        for (int p = lane; p < L; p += 64) seg[p] = sorted[s + p];
        __syncthreads();
        for (int p = lane; p < L; p += 64) {
            int v = seg[p];
            int r = 0;
            for (int q = 0; q < L; ++q) r += (seg[q] < v) ? 1 : 0;   // LDS broadcast
            inner[v] = r;
        }
    } else {  // fallback, shouldn't trigger at this input scale
        for (int p = lane; p < L; p += 64) {
            int v = sorted[s + p];
            int r = 0;
            for (int q = 0; q < L; ++q) r += (sorted[s + q] < v) ? 1 : 0;
            inner[v] = r;
        }
    }
}

// Round-1 histogram over kept voxels (keep recomputed from round-0 data).
__global__ void k_hist1(const int* __restrict__ w0, const int* __restrict__ w1,
                        const int* __restrict__ counts0, const int* __restrict__ inner0,
                        int N, int* __restrict__ counts1) {
    int i = blockIdx.x * blockDim.x + threadIdx.x;
    if (i >= N) return;
    int t, l;
    tgt_lvl(counts0[w0[i]], t, l);
    if (inner0[i] < t) atomicAdd(&counts1[w1[i]], 1);
}

// Round-1 scatter: kept voxels only.
__global__ void k_scatter1(const int* __restrict__ w0, const int* __restrict__ w1,
                           const int* __restrict__ counts0, const int* __restrict__ inner0,
                           int N, int* __restrict__ cursor, int* __restrict__ sorted) {
    int i = blockIdx.x * blockDim.x + threadIdx.x;
    if (i >= N) return;
    int t, l;
    tgt_lvl(counts0[w0[i]], t, l);
    if (inner0[i] < t) {
        int pos = atomicAdd(&cursor[w1[i]], 1);
        sorted[pos] = i;
    }
}

// Scalar outputs: keep, win0, win1, dl0, dl1, inner0, inner1 (as float32).
__global__ void k_scalars(const int* __restrict__ w0, const int* __restrict__ w1,
                          const int* __restrict__ counts0, const int* __restrict__ counts1,
                          const int* __restrict__ inner0, const int* __restrict__ inner1,
                          int N, float* __restrict__ out) {
    int i = blockIdx.x * blockDim.x + threadIdx.x;
    if (i >= N) return;
    int wi0 = w0[i], wi1 = w1[i];
    int t0, l0;
    tgt_lvl(counts0[wi0], t0, l0);
    int in0 = inner0[i];
    bool keep1 = in0 < t0;
    bool keep2 = false;
    int dl1v = -1, in1v = -1;
    if (keep1) {
        int t1, l1;
        tgt_lvl(counts1[wi1], t1, l1);
        int in1 = inner1[i];
        keep2 = in1 < t1;
        dl1v = l1;
        in1v = in1;
    }
    float* o = out + (size_t)N * 128;     // skip feat_kept
    size_t n = (size_t)N;
    o[i]         = keep2 ? 1.0f : 0.0f;   // keep
    o[n + i]     = (float)wi0;            // win0
    o[2*n + i]   = (float)wi1;            // win1
    o[3*n + i]   = (float)l0;             // dl0 (keep_in all true in round 0)
    o[4*n + i]   = (float)dl1v;           // dl1
    o[5*n + i]   = (float)in0;            // inner0
    o[6*n + i]   = (float)in1v;           // inner1
}

// Vector outputs: feat_kept (N x 128) and pe0/pe1 (N x 128). One thread = one float4.
__global__ void k_vec(const float4* __restrict__ feat, const int4* __restrict__ coords,
                      const float* __restrict__ out_base, int N, float4* __restrict__ out4) {
    int tid = blockIdx.x * blockDim.x + threadIdx.x;
    if (tid >= N * 32) return;
    int i  = tid >> 5;
    int c4 = tid & 31;

    // feat_kept
    const float* keepO = out_base + (size_t)N * 128;
    float k = keepO[i];
    float4 f = feat[tid];
    f.x *= k; f.y *= k; f.z *= k; f.w *= k;
    out4[tid] = f;

    // position embeddings
    int4 c = coords[i];
    int y = c.z, x = c.w;
    float x0 = (float)(x % 12) - 6.0f;
    float y0 = (float)(y % 12) - 6.0f;
    float x1 = (float)((x + 6) % 12) - 6.0f;
    float y1 = (float)((y + 6) % 12) - 6.0f;

    int axis = c4 >> 4;              // 0 = x-half, 1 = y-half
    int j = 2 * (c4 & 15);           // frequency index (even), pair (j, j+1)
    // inv_freq = 10000^(j/32); rf = 1/inv_freq = 2^(-j * log2(10000)/32)
    float rf0 = exp2f((float)j * -0.415241011860920285f);
    float rf1 = rf0 * 0.749894209332455847f;   // * 10000^(-1/32)

    float v0 = axis ? y0 : x0;
    float v1 = axis ? y1 : x1;
    float a0 = v0 * rf0, b0 = v0 * rf1;
    float a1 = v1 * rf0, b1 = v1 * rf1;
    float4 p0 = make_float4(__sinf(a0), __cosf(a0), __sinf(b0), __cosf(b0));
    float4 p1 = make_float4(__sinf(a1), __cosf(a1), __sinf(b1), __cosf(b1));

    size_t pe0_f4 = ((size_t)N * 135) >> 2;    // (128N + 7N) floats, in float4 units
    size_t pe1_f4 = pe0_f4 + ((size_t)N * 128 >> 2);
    out4[pe0_f4 + tid] = p0;
    out4[pe1_f4 + tid] = p1;
}

extern "C" void kernel_launch(void* const* d_in, const int* in_sizes, int n_in,
                              void* d_out, int out_size, void* d_ws, size_t ws_size,
                              hipStream_t stream) {
    const float* feat   = (const float*)d_in[0];
    const int*   coords = (const int*)d_in[1];
    int N = in_sizes[1] / 4;   // 300000

    // workspace layout (ints)
    int* counts0 = (int*)d_ws;
    int* counts1 = counts0 + NWIN;
    int* starts0 = counts1 + NWIN;
    int* cursor0 = starts0 + NWIN;
    int* starts1 = cursor0 + NWIN;
    int* cursor1 = starts1 + NWIN;
    int* w0      = cursor1 + NWIN;
    int* w1      = w0 + N;
    int* inner0  = w1 + N;
    int* inner1  = inner0 + N;
    int* sortedB = inner1 + N;   // reused for both rounds

    float* out = (float*)d_out;
    const int4*   coords4 = (const int4*)coords;
    const float4* feat4   = (const float4*)feat;

    int nb = (N + 255) / 256;

    hipMemsetAsync(d_ws, 0, 2 * NWIN * sizeof(int), stream);  // counts0 + counts1

    k_wins_hist0<<<nb, 256, 0, stream>>>(coords4, N, w0, w1, counts0);
    k_scan<<<1, 256, 0, stream>>>(counts0, starts0, cursor0);
    k_scatter0<<<nb, 256, 0, stream>>>(w0, N, cursor0, sortedB);
    k_rank<<<NWIN, 64, 0, stream>>>(starts0, counts0, sortedB, inner0);

    k_hist1<<<nb, 256, 0, stream>>>(w0, w1, counts0, inner0, N, counts1);
    k_scan<<<1, 256, 0, stream>>>(counts1, starts1, cursor1);
    k_scatter1<<<nb, 256, 0, stream>>>(w0, w1, counts0, inner0, N, cursor1, sortedB);
    k_rank<<<NWIN, 64, 0, stream>>>(starts1, counts1, sortedB, inner1);

    k_scalars<<<nb, 256, 0, stream>>>(w0, w1, counts0, counts1, inner0, inner1, N, out);
    k_vec<<<(N * 32 + 255) / 256, 256, 0, stream>>>(feat4, coords4, out, N, (float4*)d_out);
}

// Round 2
// 650.249 us; speedup vs baseline: 1.0237x; 1.0237x over previous
//
#include <hip/hip_runtime.h>

#define NWIN 12800
#define PER_SAMPLE 3200   // _NX*_NY*_NZ = 40*40*2
#define NY_NZ 80          // _NY*_NZ
#define NZW 2             // _NZ

using f4 = __attribute__((ext_vector_type(4))) float;

__device__ __forceinline__ void tgt_lvl(int nb, int& tgt, int& lvl) {
    if (nb < 16)          { tgt = 16;  lvl = 0; }
    else if (nb < 32)     { tgt = 32;  lvl = 1; }
    else if (nb < 64)     { tgt = 64;  lvl = 2; }
    else                  { tgt = 144; lvl = 3; }   // counts < 100000 always here
}

// Fused: window ids + round-0 histogram + pos-embed pe0/pe1 (streaming nt stores).
// 32 threads per voxel (one per output float4 of each pe half).
__global__ void k_pe_wins(const int4* __restrict__ coords, int N,
                          int* __restrict__ w0, int* __restrict__ w1,
                          int* __restrict__ counts0, f4* __restrict__ out4) {
    int tid = blockIdx.x * blockDim.x + threadIdx.x;
    if (tid >= N * 32) return;
    int i    = tid >> 5;
    int c4   = tid & 31;
    int lane = threadIdx.x & 63;

    int x = 0, y = 0;
    if (c4 == 0) {                      // lanes 0 and 32: one per voxel in this wave
        int4 c = coords[i];             // (b, z, y, x)
        x = c.w; y = c.z;
        int z = c.y, b = c.x;
        int wi0 = b * PER_SAMPLE + ((x + 12) / 12) * NY_NZ + ((y + 12) / 12) * NZW + z;
        int wi1 = b * PER_SAMPLE + ((x + 6)  / 12) * NY_NZ + ((y + 6)  / 12) * NZW + z;
        w0[i] = wi0;
        w1[i] = wi1;
        atomicAdd(&counts0[wi0], 1);
    }
    int src = lane & 32;                // broadcast voxel coords within each 32-lane group
    x = __shfl(x, src, 64);
    y = __shfl(y, src, 64);

    float x0 = (float)(x % 12) - 6.0f;
    float y0 = (float)(y % 12) - 6.0f;
    float x1 = (float)((x + 6) % 12) - 6.0f;
    float y1 = (float)((y + 6) % 12) - 6.0f;

    int axis = c4 >> 4;                 // 0 = x-half, 1 = y-half
    int j = 2 * (c4 & 15);              // frequency index (even); pair (j, j+1)
    // rf = 10000^(-j/32) = 2^(-j*log2(10000)/32)
    float rf0 = exp2f((float)j * -0.415241011860920285f);
    float rf1 = rf0 * 0.749894209332455847f;   // * 10000^(-1/32)

    float v0 = axis ? y0 : x0;
    float v1 = axis ? y1 : x1;
    float a0 = v0 * rf0, b0 = v0 * rf1;
    float a1 = v1 * rf0, b1 = v1 * rf1;
    f4 p0 = { __sinf(a0), __cosf(a0), __sinf(b0), __cosf(b0) };
    f4 p1 = { __sinf(a1), __cosf(a1), __sinf(b1), __cosf(b1) };

    size_t pe0_f4 = ((size_t)N * 135) >> 2;               // floats (128N + 7N) / 4
    size_t pe1_f4 = pe0_f4 + (((size_t)N * 128) >> 2);
    __builtin_nontemporal_store(p0, &out4[pe0_f4 + tid]);
    __builtin_nontemporal_store(p1, &out4[pe1_f4 + tid]);
}

// Exclusive scan over NWIN=12800 counts -> starts, and copy to cursor. One block.
__global__ void k_scan(const int* __restrict__ counts,
                       int* __restrict__ starts, int* __restrict__ cursor) {
    __shared__ int ssum[256];
    const int CH = NWIN / 256;   // 50
    int t = threadIdx.x;
    int base = t * CH;
    int s = 0;
    for (int k = 0; k < CH; ++k) s += counts[base + k];
    ssum[t] = s;
    __syncthreads();
    for (int off = 1; off < 256; off <<= 1) {
        int v = (t >= off) ? ssum[t - off] : 0;
        __syncthreads();
        ssum[t] += v;
        __syncthreads();
    }
    int run = ssum[t] - s;
    for (int k = 0; k < CH; ++k) {
        starts[base + k] = run;
        cursor[base + k] = run;
        run += counts[base + k];
    }
}

// Round-0 scatter: all voxels.
__global__ void k_scatter0(const int* __restrict__ w0, int N,
                           int* __restrict__ cursor, int* __restrict__ sorted) {
    int i = blockIdx.x * blockDim.x + threadIdx.x;
    if (i >= N) return;
    int pos = atomicAdd(&cursor[w0[i]], 1);
    sorted[pos] = i;
}

// Per-window stable rank (one wave per window), with optional fused next-round
// histogram: if w1 != nullptr, kept elements (r < tgt) bump counts1[w1[v]].
__global__ void k_rank(const int* __restrict__ starts, const int* __restrict__ counts,
                       const int* __restrict__ sorted, int* __restrict__ inner,
                       const int* __restrict__ w1, int* __restrict__ counts1) {
    __shared__ int seg[1024];
    int w = blockIdx.x;
    int L = counts[w];
    if (L == 0) return;
    int s = starts[w];
    int lane = threadIdx.x;
    int tgt, lvl;
    tgt_lvl(L, tgt, lvl);
    if (L <= 1024) {
        for (int p = lane; p < L; p += 64) seg[p] = sorted[s + p];
        __syncthreads();
        for (int p = lane; p < L; p += 64) {
            int v = seg[p];
            int r = 0;
            for (int q = 0; q < L; ++q) r += (seg[q] < v) ? 1 : 0;   // LDS broadcast
            inner[v] = r;
            if (w1 != nullptr && r < tgt) atomicAdd(&counts1[w1[v]], 1);
        }
    } else {  // fallback; not expected at this scale
        for (int p = lane; p < L; p += 64) {
            int v = sorted[s + p];
            int r = 0;
            for (int q = 0; q < L; ++q) r += (sorted[s + q] < v) ? 1 : 0;
            inner[v] = r;
            if (w1 != nullptr && r < tgt) atomicAdd(&counts1[w1[v]], 1);
        }
    }
}

// Round-1 scatter: kept voxels only (keep recomputed from round-0 data).
__global__ void k_scatter1(const int* __restrict__ w0, const int* __restrict__ w1,
                           const int* __restrict__ counts0, const int* __restrict__ inner0,
                           int N, int* __restrict__ cursor, int* __restrict__ sorted) {
    int i = blockIdx.x * blockDim.x + threadIdx.x;
    if (i >= N) return;
    int t, l;
    tgt_lvl(counts0[w0[i]], t, l);
    if (inner0[i] < t) {
        int pos = atomicAdd(&cursor[w1[i]], 1);
        sorted[pos] = i;
    }
}

// Scalar outputs: keep, win0, win1, dl0, dl1, inner0, inner1 (as float32).
__global__ void k_scalars(const int* __restrict__ w0, const int* __restrict__ w1,
                          const int* __restrict__ counts0, const int* __restrict__ counts1,
                          const int* __restrict__ inner0, const int* __restrict__ inner1,
                          int N, float* __restrict__ out) {
    int i = blockIdx.x * blockDim.x + threadIdx.x;
    if (i >= N) return;
    int wi0 = w0[i], wi1 = w1[i];
    int t0, l0;
    tgt_lvl(counts0[wi0], t0, l0);
    int in0 = inner0[i];
    bool keep1 = in0 < t0;
    bool keep2 = false;
    int dl1v = -1, in1v = -1;
    if (keep1) {
        int t1, l1;
        tgt_lvl(counts1[wi1], t1, l1);
        int in1 = inner1[i];
        keep2 = in1 < t1;
        dl1v = l1;
        in1v = in1;
    }
    float* o = out + (size_t)N * 128;     // skip feat_kept
    size_t n = (size_t)N;
    o[i]         = keep2 ? 1.0f : 0.0f;   // keep
    o[n + i]     = (float)wi0;            // win0
    o[2*n + i]   = (float)wi1;            // win1
    o[3*n + i]   = (float)l0;             // dl0
    o[4*n + i]   = (float)dl1v;           // dl1
    o[5*n + i]   = (float)in0;            // inner0
    o[6*n + i]   = (float)in1v;           // inner1
}

// feat_kept: pure streaming, nt load + nt store, keep broadcast via shuffle.
__global__ void k_feat(const f4* __restrict__ feat, const float* __restrict__ keepO,
                       int N, f4* __restrict__ out4) {
    int tid = blockIdx.x * blockDim.x + threadIdx.x;
    if (tid >= N * 32) return;
    int i    = tid >> 5;
    int lane = threadIdx.x & 63;
    float k = 0.0f;
    if ((tid & 31) == 0) k = keepO[i];
    k = __shfl(k, lane & 32, 64);
    f4 f = __builtin_nontemporal_load(&feat[tid]);
    f *= k;
    __builtin_nontemporal_store(f, &out4[tid]);
}

extern "C" void kernel_launch(void* const* d_in, const int* in_sizes, int n_in,
                              void* d_out, int out_size, void* d_ws, size_t ws_size,
                              hipStream_t stream) {
    const float* feat   = (const float*)d_in[0];
    const int*   coords = (const int*)d_in[1];
    int N = in_sizes[1] / 4;   // 300000

    // workspace layout (ints)
    int* counts0 = (int*)d_ws;
    int* counts1 = counts0 + NWIN;
    int* starts0 = counts1 + NWIN;
    int* cursor0 = starts0 + NWIN;
    int* starts1 = cursor0 + NWIN;
    int* cursor1 = starts1 + NWIN;
    int* w0      = cursor1 + NWIN;
    int* w1      = w0 + N;
    int* inner0  = w1 + N;
    int* inner1  = inner0 + N;
    int* sortedB = inner1 + N;   // reused for both rounds

    float* out = (float*)d_out;
    const int4* coords4 = (const int4*)coords;
    const f4*   feat4   = (const f4*)feat;

    int nb  = (N + 255) / 256;
    int nb32 = (N * 32 + 255) / 256;

    hipMemsetAsync(d_ws, 0, 2 * NWIN * sizeof(int), stream);  // counts0 + counts1

    k_pe_wins<<<nb32, 256, 0, stream>>>(coords4, N, w0, w1, counts0, (f4*)d_out);
    k_scan<<<1, 256, 0, stream>>>(counts0, starts0, cursor0);
    k_scatter0<<<nb, 256, 0, stream>>>(w0, N, cursor0, sortedB);
    k_rank<<<NWIN, 64, 0, stream>>>(starts0, counts0, sortedB, inner0, w1, counts1); // + hist1
    k_scan<<<1, 256, 0, stream>>>(counts1, starts1, cursor1);
    k_scatter1<<<nb, 256, 0, stream>>>(w0, w1, counts0, inner0, N, cursor1, sortedB);
    k_rank<<<NWIN, 64, 0, stream>>>(starts1, counts1, sortedB, inner1, nullptr, nullptr);
    k_scalars<<<nb, 256, 0, stream>>>(w0, w1, counts0, counts1, inner0, inner1, N, out);
    k_feat<<<nb32, 256, 0, stream>>>(feat4, out + (size_t)N * 128, N, (f4*)d_out);
}

// Round 3
// 642.913 us; speedup vs baseline: 1.0354x; 1.0114x over previous
//
#include <hip/hip_runtime.h>

#define NWIN 12800
#define PER_SAMPLE 3200   // _NX*_NY*_NZ = 40*40*2
#define NY_NZ 80          // _NY*_NZ
#define NZW 2             // _NZ

using f4 = __attribute__((ext_vector_type(4))) float;

__device__ __forceinline__ void tgt_lvl(int nb, int& tgt, int& lvl) {
    if (nb < 16)          { tgt = 16;  lvl = 0; }
    else if (nb < 32)     { tgt = 32;  lvl = 1; }
    else if (nb < 64)     { tgt = 64;  lvl = 2; }
    else                  { tgt = 144; lvl = 3; }   // counts < 100000 always here
}

// Fused: window ids + round-0 histogram + pe0/pe1 (streaming nt stores).
// 16 threads per voxel; each thread writes 2 float4 per pe array.
__global__ void k_pe_wins(const int4* __restrict__ coords, int N,
                          int* __restrict__ w0, int* __restrict__ w1,
                          int* __restrict__ counts0, f4* __restrict__ out4) {
    int tid = blockIdx.x * blockDim.x + threadIdx.x;
    if (tid >= N * 16) return;
    int i    = tid >> 4;
    int c4   = tid & 15;           // chunk index within each 64-float half
    int lane = threadIdx.x & 63;

    int x = 0, y = 0;
    if (c4 == 0) {                 // 4 loader lanes per wave (0,16,32,48)
        int4 c = coords[i];        // (b, z, y, x)
        x = c.w; y = c.z;
        int wi0 = c.x * PER_SAMPLE + ((x + 12) / 12) * NY_NZ + ((y + 12) / 12) * NZW + c.y;
        int wi1 = c.x * PER_SAMPLE + ((x + 6)  / 12) * NY_NZ + ((y + 6)  / 12) * NZW + c.y;
        w0[i] = wi0;
        w1[i] = wi1;
        atomicAdd(&counts0[wi0], 1);
    }
    int src = lane & 48;           // broadcast within each 16-lane group
    x = __shfl(x, src, 64);
    y = __shfl(y, src, 64);

    float x0 = (float)(x % 12) - 6.0f;
    float y0 = (float)(y % 12) - 6.0f;
    float x1 = (float)((x + 6) % 12) - 6.0f;
    float y1 = (float)((y + 6) % 12) - 6.0f;

    // chunk c4 covers freq pair (2*c4, 2*c4+1); rf = 10000^(-k/32)
    float rf0 = exp2f((float)(2 * c4) * -0.415241011860920285f);
    float rf1 = rf0 * 0.749894209332455847f;   // * 10000^(-1/32)

    float ax0 = x0 * rf0, bx0 = x0 * rf1, ay0 = y0 * rf0, by0 = y0 * rf1;
    float ax1 = x1 * rf0, bx1 = x1 * rf1, ay1 = y1 * rf0, by1 = y1 * rf1;
    f4 p0x = { __sinf(ax0), __cosf(ax0), __sinf(bx0), __cosf(bx0) };
    f4 p0y = { __sinf(ay0), __cosf(ay0), __sinf(by0), __cosf(by0) };
    f4 p1x = { __sinf(ax1), __cosf(ax1), __sinf(bx1), __cosf(bx1) };
    f4 p1y = { __sinf(ay1), __cosf(ay1), __sinf(by1), __cosf(by1) };

    size_t pe0 = ((size_t)N * 135) >> 2;               // float4 offset of pe0
    size_t pe1 = pe0 + (((size_t)N * 128) >> 2);
    size_t vb  = (size_t)i * 32 + c4;
    __builtin_nontemporal_store(p0x, &out4[pe0 + vb]);        // x-half chunk
    __builtin_nontemporal_store(p0y, &out4[pe0 + vb + 16]);   // y-half chunk
    __builtin_nontemporal_store(p1x, &out4[pe1 + vb]);
    __builtin_nontemporal_store(p1y, &out4[pe1 + vb + 16]);
}

// Exclusive scan over NWIN=12800 counts -> starts, and copy to cursor. One block.
__global__ void k_scan(const int* __restrict__ counts,
                       int* __restrict__ starts, int* __restrict__ cursor) {
    __shared__ int ssum[256];
    const int CH = NWIN / 256;   // 50
    int t = threadIdx.x;
    int base = t * CH;
    int s = 0;
    for (int k = 0; k < CH; ++k) s += counts[base + k];
    ssum[t] = s;
    __syncthreads();
    for (int off = 1; off < 256; off <<= 1) {
        int v = (t >= off) ? ssum[t - off] : 0;
        __syncthreads();
        ssum[t] += v;
        __syncthreads();
    }
    int run = ssum[t] - s;
    for (int k = 0; k < CH; ++k) {
        starts[base + k] = run;
        cursor[base + k] = run;
        run += counts[base + k];
    }
}

// Round-0 scatter: all voxels.
__global__ void k_scatter0(const int* __restrict__ w0, int N,
                           int* __restrict__ cursor, int* __restrict__ sorted) {
    int i = blockIdx.x * blockDim.x + threadIdx.x;
    if (i >= N) return;
    int pos = atomicAdd(&cursor[w0[i]], 1);
    sorted[pos] = i;
}

// Per-window stable rank (one wave per window); optional fused next-round histogram.
__global__ void k_rank(const int* __restrict__ starts, const int* __restrict__ counts,
                       const int* __restrict__ sorted, int* __restrict__ inner,
                       const int* __restrict__ w1, int* __restrict__ counts1) {
    __shared__ int seg[1024];
    int w = blockIdx.x;
    int L = counts[w];
    if (L == 0) return;
    int s = starts[w];
    int lane = threadIdx.x;
    int tgt, lvl;
    tgt_lvl(L, tgt, lvl);
    if (L <= 1024) {
        for (int p = lane; p < L; p += 64) seg[p] = sorted[s + p];
        __syncthreads();
        for (int p = lane; p < L; p += 64) {
            int v = seg[p];
            int r = 0;
            for (int q = 0; q < L; ++q) r += (seg[q] < v) ? 1 : 0;   // LDS broadcast
            inner[v] = r;
            if (w1 != nullptr && r < tgt) atomicAdd(&counts1[w1[v]], 1);
        }
    } else {  // fallback; not expected at this scale
        for (int p = lane; p < L; p += 64) {
            int v = sorted[s + p];
            int r = 0;
            for (int q = 0; q < L; ++q) r += (sorted[s + q] < v) ? 1 : 0;
            inner[v] = r;
            if (w1 != nullptr && r < tgt) atomicAdd(&counts1[w1[v]], 1);
        }
    }
}

// Round-1 scatter: kept voxels only (keep recomputed from round-0 data).
__global__ void k_scatter1(const int* __restrict__ w0, const int* __restrict__ w1,
                           const int* __restrict__ counts0, const int* __restrict__ inner0,
                           int N, int* __restrict__ cursor, int* __restrict__ sorted) {
    int i = blockIdx.x * blockDim.x + threadIdx.x;
    if (i >= N) return;
    int t, l;
    tgt_lvl(counts0[w0[i]], t, l);
    if (inner0[i] < t) {
        int pos = atomicAdd(&cursor[w1[i]], 1);
        sorted[pos] = i;
    }
}

// Fused final pass: feat_kept (streaming) + all 7 scalar channels.
// 16 threads per voxel; lane c4==0 computes keep/dl/inner and writes scalars.
__global__ void k_final(const f4* __restrict__ feat,
                        const int* __restrict__ w0, const int* __restrict__ w1,
                        const int* __restrict__ counts0, const int* __restrict__ counts1,
                        const int* __restrict__ inner0, const int* __restrict__ inner1,
                        int N, f4* __restrict__ out4, float* __restrict__ out) {
    int tid = blockIdx.x * blockDim.x + threadIdx.x;
    if (tid >= N * 16) return;
    int i    = tid >> 4;
    int c4   = tid & 15;
    int lane = threadIdx.x & 63;

    float k = 0.0f;
    if (c4 == 0) {
        int wi0 = w0[i], wi1 = w1[i];
        int t0, l0;
        tgt_lvl(counts0[wi0], t0, l0);
        int in0 = inner0[i];
        bool keep1 = in0 < t0;
        bool keep2 = false;
        int dl1v = -1, in1v = -1;
        if (keep1) {
            int t1, l1;
            tgt_lvl(counts1[wi1], t1, l1);
            int in1 = inner1[i];
            keep2 = in1 < t1;
            dl1v = l1;
            in1v = in1;
        }
        k = keep2 ? 1.0f : 0.0f;
        float* o = out + (size_t)N * 128;
        size_t n = (size_t)N;
        o[i]       = k;
        o[n + i]   = (float)wi0;
        o[2*n + i] = (float)wi1;
        o[3*n + i] = (float)l0;
        o[4*n + i] = (float)dl1v;
        o[5*n + i] = (float)in0;
        o[6*n + i] = (float)in1v;
    }
    k = __shfl(k, lane & 48, 64);

    size_t vb = (size_t)i * 32 + c4;
    f4 fa = __builtin_nontemporal_load(&feat[vb]);
    f4 fb = __builtin_nontemporal_load(&feat[vb + 16]);
    fa *= k;
    fb *= k;
    __builtin_nontemporal_store(fa, &out4[vb]);
    __builtin_nontemporal_store(fb, &out4[vb + 16]);
}

extern "C" void kernel_launch(void* const* d_in, const int* in_sizes, int n_in,
                              void* d_out, int out_size, void* d_ws, size_t ws_size,
                              hipStream_t stream) {
    const float* feat   = (const float*)d_in[0];
    const int*   coords = (const int*)d_in[1];
    int N = in_sizes[1] / 4;   // 300000

    // workspace layout (ints)
    int* counts0 = (int*)d_ws;
    int* counts1 = counts0 + NWIN;
    int* starts0 = counts1 + NWIN;
    int* cursor0 = starts0 + NWIN;
    int* starts1 = cursor0 + NWIN;
    int* cursor1 = starts1 + NWIN;
    int* w0      = cursor1 + NWIN;
    int* w1      = w0 + N;
    int* inner0  = w1 + N;
    int* inner1  = inner0 + N;
    int* sortedB = inner1 + N;   // reused for both rounds

    float* out = (float*)d_out;
    const int4* coords4 = (const int4*)coords;
    const f4*   feat4   = (const f4*)feat;

    int nb   = (N + 255) / 256;
    int nb16 = (N * 16 + 255) / 256;

    hipMemsetAsync(d_ws, 0, 2 * NWIN * sizeof(int), stream);  // counts0 + counts1

    k_pe_wins<<<nb16, 256, 0, stream>>>(coords4, N, w0, w1, counts0, (f4*)d_out);
    k_scan<<<1, 256, 0, stream>>>(counts0, starts0, cursor0);
    k_scatter0<<<nb, 256, 0, stream>>>(w0, N, cursor0, sortedB);
    k_rank<<<NWIN, 64, 0, stream>>>(starts0, counts0, sortedB, inner0, w1, counts1); // + hist1
    k_scan<<<1, 256, 0, stream>>>(counts1, starts1, cursor1);
    k_scatter1<<<nb, 256, 0, stream>>>(w0, w1, counts0, inner0, N, cursor1, sortedB);
    k_rank<<<NWIN, 64, 0, stream>>>(starts1, counts1, sortedB, inner1, nullptr, nullptr);
    k_final<<<nb16, 256, 0, stream>>>(feat4, w0, w1, counts0, counts1, inner0, inner1,
                                      N, (f4*)d_out, out);
}